// Round 15
// baseline (1774.825 us; speedup 1.0000x reference)
//
#include <hip/hip_runtime.h>
#include <math.h>

// Residual VQ: x (262144,128) fp32, codebooks (3,256,128) fp32.
// Output: [indices as float (262144*3)] ++ [quantized (262144*128)].
//
// ARITHMETIC CONTRACT (absmax=0 — do not change):
//   M_k  = OpenBLAS sgemm K-loop: sequential FMA chain j=0..127, acc init 0
//   A    = np.sum(r*r): pairwise_sum 8-accumulator scheme, products rounded
//          separately (fmaf(x,x,0) = single-rounded product, blocks fusion)
//   d2_k = (A - 2.0f*M_k) + B_k ; argmin strict < ascending k
//          (fmaf(-2,M,A)+B == (A-2.0f*M)+B bit-exact)
//   residual: r1 = x - q0, r2 = r1 - q1 — in-place global scratch, ref order
//   quantized = (q0 + q1) + q2 elementwise fp32, ref order
//
// ROUND 19 CHANGE: r18 refuted the pipe-split (phases serialize within a
// wave; 8 waves can't overlap them). The DS route is structurally capped
// (1 uniform ds_read_b128 per 4 FMA-winstr on the per-CU DS pipe >= 1.3ms).
// The scalar route's 780us stall is K$ misses, and those are self-inflicted:
// r12's 4 waves/block sweep 4 DISJOINT 16KB slabs -> per-CU K$ demand 16
// waves x disjoint >> 16KB. Fix: block = 256 items, ONE PER THREAD; all 4
// waves sweep the SAME 32-entry subtile in phase (s_barrier per subtile
// keeps them K$-locked; subtile = 16KB = exactly K$, shared 4-ways -> ~4x
// fewer misses). Each thread argmins all 256 entries itself: cross-wave
// combine, its LDS buffers, and ALL __syncthreads are deleted (LDS = 0;
// scratch is thread-private, program-order). Residual re-reads rise to 8
// sweeps/cb — L2-resident (block slice 128KB), ~90us of L2 BW. Same MROW
// chains, fused A, strict-< ascending argmin (now trivially numpy's
// thread-local first-min), bound 4 (VGPR cap 128, working set ~72),
// grid 1024 = 4 blocks/CU = 16 waves/CU.

constexpr int kItems = 262144;
constexpr int kDim   = 128;
constexpr int kNcb   = 3;
constexpr int kK     = 256;
constexpr int kBlock = 256;
constexpr int kIPB   = 256;        // items per block (one per THREAD)
constexpr int TE     = 32;         // entries per sub-tile (named accumulators)
constexpr int NST    = kK / TE;    // 8 subtiles, swept by ALL waves in phase
constexpr int NJC    = kDim / 8;   // 16 dim-chunks of 8

__device__ __forceinline__ float sq_rn(float x) {
    return __builtin_fmaf(x, x, 0.0f);
}

// numpy pairwise_sum, n=128 (for the B-table)
template <typename F>
__device__ __forceinline__ float np_pairwise128(F term) {
    float r0 = term(0), r1 = term(1), r2 = term(2), r3 = term(3),
          r4 = term(4), r5 = term(5), r6 = term(6), r7 = term(7);
    #pragma unroll
    for (int i = 8; i < 128; i += 8) {
        r0 = r0 + term(i + 0); r1 = r1 + term(i + 1);
        r2 = r2 + term(i + 2); r3 = r3 + term(i + 3);
        r4 = r4 + term(i + 4); r5 = r5 + term(i + 5);
        r6 = r6 + term(i + 6); r7 = r7 + term(i + 7);
    }
    return ((r0 + r1) + (r2 + r3)) + ((r4 + r5) + (r6 + r7));
}

// ---------- pre-kernel: B_k = np.sum(cb*cb, axis=-1) into d_ws (768 floats)
__global__ void rvq_btable(const float* __restrict__ cb,
                           float* __restrict__ Bt)
{
    const int m = blockIdx.x * 256 + threadIdx.x;   // 3 blocks x 256 = 768
    const float* row = cb + (size_t)m * kDim;
    Bt[m] = np_pairwise128([&](int j) { return sq_rn(row[j]); });
}

#define X32(X) X(0) X(1) X(2) X(3) X(4) X(5) X(6) X(7) \
  X(8) X(9) X(10) X(11) X(12) X(13) X(14) X(15) \
  X(16) X(17) X(18) X(19) X(20) X(21) X(22) X(23) \
  X(24) X(25) X(26) X(27) X(28) X(29) X(30) X(31)

// 32 entries x 8 dims; typed float4 uniform loads (merged s_load path —
// cbT is block-uniform, so all 4 waves hit the SAME K$ lines);
// per-entry FMA chain stays sequential in j
#define MROW(e) { \
    const float4* rp = (const float4*)(cbT + (size_t)(e) * kDim); \
    const float4 ca = rp[2*jc], cd = rp[2*jc+1]; \
    m##e = __builtin_fmaf(ra.x, ca.x, m##e); \
    m##e = __builtin_fmaf(ra.y, ca.y, m##e); \
    m##e = __builtin_fmaf(ra.z, ca.z, m##e); \
    m##e = __builtin_fmaf(ra.w, ca.w, m##e); \
    m##e = __builtin_fmaf(rb.x, cd.x, m##e); \
    m##e = __builtin_fmaf(rb.y, cd.y, m##e); \
    m##e = __builtin_fmaf(rb.z, cd.z, m##e); \
    m##e = __builtin_fmaf(rb.w, cd.w, m##e); }

#define MDECL(e) float m##e = 0.0f;

#define EPI(e) { \
    float tt = __builtin_fmaf(-2.0f, m##e, A) + Bt[c * kK + kb + (e)]; \
    if (tt < best) { best = tt; bi = kb + (e); } }

// one 32-entry sub-tile, s_load-fed, residual software-pipelined (r13)
#define SUBTILE(KB, DO_A) { \
    const int kb = (KB); \
    const float* cbT = cb + ((size_t)c * kK + kb) * kDim; \
    X32(MDECL) \
    float a0 = 0.f, a1 = 0.f, a2 = 0.f, a3 = 0.f, \
          a4 = 0.f, a5 = 0.f, a6 = 0.f, a7 = 0.f; \
    float4 ra = rrow4[0], rb = rrow4[1]; \
    _Pragma("unroll 1") \
    for (int jc = 0; jc < NJC; ++jc) { \
        float4 na = ra, nb = rb; \
        if (jc < NJC - 1) { na = rrow4[2*jc+2]; nb = rrow4[2*jc+3]; } \
        if (DO_A) { \
            a0 = a0 + sq_rn(ra.x); a1 = a1 + sq_rn(ra.y); \
            a2 = a2 + sq_rn(ra.z); a3 = a3 + sq_rn(ra.w); \
            a4 = a4 + sq_rn(rb.x); a5 = a5 + sq_rn(rb.y); \
            a6 = a6 + sq_rn(rb.z); a7 = a7 + sq_rn(rb.w); \
        } \
        X32(MROW) \
        ra = na; rb = nb; \
    } \
    if (DO_A) \
        A = ((a0 + a1) + (a2 + a3)) + ((a4 + a5) + (a6 + a7)); \
    X32(EPI) \
}

__global__ __launch_bounds__(kBlock, 4) void rvq_kernel(
    const float* __restrict__ x,
    const float* __restrict__ cb,
    const float* __restrict__ Bt,
    float* __restrict__ out)
{
    const int t = threadIdx.x;
    const int item = blockIdx.x * kIPB + t;   // one item per thread

    float* out_idx = out;                             // (items, 3) as float
    float* out_q   = out + (size_t)kItems * kNcb;     // (items, 128)

    const float* xrow = x + (size_t)item * kDim;      // cb0 residual
    float*       qrow = out_q + (size_t)item * kDim;  // cb1/2 residual scratch
                                                      // (thread-private rows)
    int sel0 = 0, sel1 = 0, sel2 = 0;

    #pragma unroll 1
    for (int c = 0; c < kNcb; ++c) {
        const float* rrow = (c == 0) ? xrow : (const float*)qrow;
        const float4* rrow4 = (const float4*)rrow;

        float A = 0.0f;
        float best = INFINITY;
        int bi = 0;

        // subtile 0 (A fused), then 1..7 — ALL waves sweep the same subtile;
        // s_barrier (no memory semantics needed: no LDS, scratch is
        // thread-private) keeps the 4 waves phase-locked on one 16KB K$ set
        SUBTILE(0, 1)
        #pragma unroll 1
        for (int st = 1; st < NST; ++st) {
            __builtin_amdgcn_s_barrier();
            SUBTILE(st * TE, 0)
        }

        if (c == 0) sel0 = bi; else if (c == 1) sel1 = bi; else sel2 = bi;

        // ---- residual update, thread-private (no barrier needed: only this
        // thread reads qrow next iteration; program order suffices)
        if (c < 2) {
            const int sel = (c == 0) ? sel0 : sel1;
            const float4* cw4 =
                (const float4*)(cb + ((size_t)c * kK + sel) * kDim);
            const float4* srow4 = (c == 0) ? (const float4*)xrow
                                           : (const float4*)qrow;
            float4* drow4 = (float4*)qrow;
            #pragma unroll 8
            for (int i2 = 0; i2 < 32; ++i2) {
                const float4 w = cw4[i2];
                float4 rv = srow4[i2];
                rv.x = rv.x - w.x;  rv.y = rv.y - w.y;   // one rounding each,
                rv.z = rv.z - w.z;  rv.w = rv.w - w.w;   // ref order
                drow4[i2] = rv;
            }
        }
    }

    // ---- outputs (thread-private; overwrite the scratch with final q)
    out_idx[(size_t)item * kNcb + 0] = (float)sel0;
    out_idx[(size_t)item * kNcb + 1] = (float)sel1;
    out_idx[(size_t)item * kNcb + 2] = (float)sel2;

    {
        const float4* q0v = (const float4*)(cb + ((size_t)0 * kK + sel0) * kDim);
        const float4* q1v = (const float4*)(cb + ((size_t)1 * kK + sel1) * kDim);
        const float4* q2v = (const float4*)(cb + ((size_t)2 * kK + sel2) * kDim);
        float4* qov = (float4*)qrow;
        #pragma unroll 8
        for (int i2 = 0; i2 < 32; ++i2) {
            const float4 u = q0v[i2], v = q1v[i2], w = q2v[i2];
            float4 o;
            o.x = (u.x + v.x) + w.x;
            o.y = (u.y + v.y) + w.y;
            o.z = (u.z + v.z) + w.z;
            o.w = (u.w + v.w) + w.w;
            qov[i2] = o;   // ((0+q0)+q1)+q2 in fp32, ref order
        }
    }
}

extern "C" void kernel_launch(void* const* d_in, const int* in_sizes, int n_in,
                              void* d_out, int out_size, void* d_ws, size_t ws_size,
                              hipStream_t stream) {
    const float* x  = (const float*)d_in[0];
    const float* cb = (const float*)d_in[1];
    float* out = (float*)d_out;
    float* Bt  = (float*)d_ws;     // 768 floats
    rvq_btable<<<kNcb, 256, 0, stream>>>(cb, Bt);
    rvq_kernel<<<kItems / kIPB, kBlock, 0, stream>>>(x, cb, Bt, out);
}

// Round 16
// 1150.492 us; speedup vs baseline: 1.5427x; 1.5427x over previous
//
#include <hip/hip_runtime.h>
#include <math.h>

// Residual VQ: x (262144,128) fp32, codebooks (3,256,128) fp32.
// Output: [indices as float (262144*3)] ++ [quantized (262144*128)].
//
// ARITHMETIC CONTRACT (absmax=0 — do not change):
//   M_k  = OpenBLAS sgemm K-loop: sequential FMA chain j=0..127, acc init 0
//   A    = np.sum(r*r): pairwise_sum 8-accumulator scheme, products rounded
//          separately (fmaf(x,x,0) = single-rounded product, blocks fusion)
//   d2_k = (A - 2.0f*M_k) + B_k ; argmin strict < ascending k == first-min
//          (implemented as per-lane v-ascending strict-< then (val,idx)
//           shuffle-reduce with tie -> smaller idx: identical semantics)
//   residual: r1 = x - q0, r2 = r1 - q1 — in-place global scratch, ref order
//   quantized = (q0 + q1) + q2 elementwise fp32, ref order
//
// ROUND 20 CHANGE: rounds 11/12/17/18/19 mapped items to lanes, making every
// codebook float a BROADCAST operand feeding exactly ONE FMA wave-instr —
// so the operand stream must run at FMA rate on some pipe; scalar (K$
// latency), DS (1 ds_read/4 FMA throughput), and per-lane VMEM all saturate
// at ~1.2ms. This round inverts the mapping (GEMM register tiling): lane =
// ENTRY (lane l owns entries {64v+l}), codebook tile in VGPRs. Per phase
// (4 dims): 16 coalesced dword loads of transposed cbT[j][64v+lane] are each
// reused by 16 items -> 16 FMAs per codebook float (was 1). The residual is
// now the broadcast side: one same-address float4 load per item-phase (HW
// broadcast, L1-hit, wave-private rows). 32 loads : 272 FMAs per phase, all
// L1/L2-resident. Chain order per acc = phases x dims = j ascending (exact).
// A per-lane (lane i owns item i), __shfl broadcast. Argmin via shfl_xor
// (val,idx) reduce. No LDS, no barriers; scratch is wave-private with
// explicit vmcnt(0) before the next cb reads it (compiler keeps these VMEM:
// stores through out_q alias the loads, so no s_load/K$-staleness path).
// batch=16, bound (256,2): need ~100 VGPR < cap 128.

constexpr int kItems = 262144;
constexpr int kDim   = 128;
constexpr int kNcb   = 3;
constexpr int kK     = 256;
constexpr int kBlock = 256;
constexpr int kBatch = 16;        // items per wave (wave-private batch)
constexpr int NPH    = 32;        // phases of 4 dims

__device__ __forceinline__ float sq_rn(float x) {
    return __builtin_fmaf(x, x, 0.0f);
}

// numpy pairwise_sum, n=128 (for the B-table)
template <typename F>
__device__ __forceinline__ float np_pairwise128(F term) {
    float r0 = term(0), r1 = term(1), r2 = term(2), r3 = term(3),
          r4 = term(4), r5 = term(5), r6 = term(6), r7 = term(7);
    #pragma unroll
    for (int i = 8; i < 128; i += 8) {
        r0 = r0 + term(i + 0); r1 = r1 + term(i + 1);
        r2 = r2 + term(i + 2); r3 = r3 + term(i + 3);
        r4 = r4 + term(i + 4); r5 = r5 + term(i + 5);
        r6 = r6 + term(i + 6); r7 = r7 + term(i + 7);
    }
    return ((r0 + r1) + (r2 + r3)) + ((r4 + r5) + (r6 + r7));
}

// ---------- pre-kernel: Bt (768 floats) + transposed codebook cbT:
// cbT[(c*128 + j)*256 + e] = cb[(c*256 + e)*128 + j]
__global__ void rvq_prep(const float* __restrict__ cb,
                         float* __restrict__ Bt,
                         float* __restrict__ cbT)
{
    const int tid = blockIdx.x * 256 + threadIdx.x;   // 384*256 = 98304
    const int e = tid & 255;
    const int j = (tid >> 8) & 127;
    const int c = tid >> 15;
    cbT[tid] = cb[((size_t)c * kK + e) * kDim + j];
    if (tid < kNcb * kK) {
        const float* row = cb + (size_t)tid * kDim;
        Bt[tid] = np_pairwise128([&](int jj) { return sq_rn(row[jj]); });
    }
}

#define X16(X) X(0) X(1) X(2) X(3) X(4) X(5) X(6) X(7) \
  X(8) X(9) X(10) X(11) X(12) X(13) X(14) X(15)

#define MDECL(i) float m##i##_0 = 0.f, m##i##_1 = 0.f, \
                       m##i##_2 = 0.f, m##i##_3 = 0.f;

// one item's phase step: broadcast residual float4 (same addr all lanes),
// 16 FMAs; per-acc chain = d ascending within phase, phases ascending -> j
// = 0..127 sequential (OpenBLAS K-loop order, bit-exact)
#define MITEM(i) { \
    const float4 rv = *(const float4*)(rb_ + (size_t)(i) * kDim + 4 * p); \
    m##i##_0 = __builtin_fmaf(rv.x, cb0_0, m##i##_0); \
    m##i##_0 = __builtin_fmaf(rv.y, cb1_0, m##i##_0); \
    m##i##_0 = __builtin_fmaf(rv.z, cb2_0, m##i##_0); \
    m##i##_0 = __builtin_fmaf(rv.w, cb3_0, m##i##_0); \
    m##i##_1 = __builtin_fmaf(rv.x, cb0_1, m##i##_1); \
    m##i##_1 = __builtin_fmaf(rv.y, cb1_1, m##i##_1); \
    m##i##_1 = __builtin_fmaf(rv.z, cb2_1, m##i##_1); \
    m##i##_1 = __builtin_fmaf(rv.w, cb3_1, m##i##_1); \
    m##i##_2 = __builtin_fmaf(rv.x, cb0_2, m##i##_2); \
    m##i##_2 = __builtin_fmaf(rv.y, cb1_2, m##i##_2); \
    m##i##_2 = __builtin_fmaf(rv.z, cb2_2, m##i##_2); \
    m##i##_2 = __builtin_fmaf(rv.w, cb3_2, m##i##_2); \
    m##i##_3 = __builtin_fmaf(rv.x, cb0_3, m##i##_3); \
    m##i##_3 = __builtin_fmaf(rv.y, cb1_3, m##i##_3); \
    m##i##_3 = __builtin_fmaf(rv.z, cb2_3, m##i##_3); \
    m##i##_3 = __builtin_fmaf(rv.w, cb3_3, m##i##_3); }

// d2 + argmin for item i: per-lane candidates v ascending (strict < keeps
// lowest idx), then 6-step (val,idx) butterfly reduce, tie -> smaller idx
// == numpy first-min over all 256 entries
#define ARGMIN(i) { \
    const float Ai = __shfl(Areg, (i)); \
    float bv = __builtin_fmaf(-2.0f, m##i##_0, Ai) + B0; \
    int   bx = lane; \
    float dd = __builtin_fmaf(-2.0f, m##i##_1, Ai) + B1; \
    if (dd < bv) { bv = dd; bx = 64 + lane; } \
    dd = __builtin_fmaf(-2.0f, m##i##_2, Ai) + B2; \
    if (dd < bv) { bv = dd; bx = 128 + lane; } \
    dd = __builtin_fmaf(-2.0f, m##i##_3, Ai) + B3; \
    if (dd < bv) { bv = dd; bx = 192 + lane; } \
    _Pragma("unroll") \
    for (int off = 32; off; off >>= 1) { \
        const float ov = __shfl_xor(bv, off); \
        const int   ox = __shfl_xor(bx, off); \
        const bool take = (ov < bv) || (ov == bv && ox < bx); \
        bv = take ? ov : bv; bx = take ? ox : bx; \
    } \
    if (c == 0)      sel0 = (lane == (i)) ? bx : sel0; \
    else if (c == 1) sel1 = (lane == (i)) ? bx : sel1; \
    else             sel2 = (lane == (i)) ? bx : sel2; }

__global__ __launch_bounds__(kBlock, 2) void rvq_kernel(
    const float* __restrict__ x,
    const float* __restrict__ cb,
    const float* __restrict__ Bt,
    const float* __restrict__ cbT,
    float* __restrict__ out)
{
    const int t = threadIdx.x;
    const int lane = t & 63;
    // global wave id = batch id; each wave fully independent (no LDS, no bar)
    const int wid = blockIdx.x * (kBlock / 64) + (t >> 6);
    const size_t ibase = (size_t)wid * kBatch;

    float* out_idx = out;                             // (items, 3) as float
    float* out_q   = out + (size_t)kItems * kNcb;     // (items, 128)

    const float* xb = x + ibase * kDim;               // batch x rows
    float*       qb = out_q + ibase * kDim;           // batch scratch rows

    int sel0 = 0, sel1 = 0, sel2 = 0;                 // lane i: item i's sel

    #pragma unroll 1
    for (int c = 0; c < kNcb; ++c) {
        const float* rb_ = (c == 0) ? xb : (const float*)qb;
        const float* cbTc = cbT + (size_t)c * kDim * kK;

        // ---- A: lane i computes item i's np.sum(r*r), 8-stripe pairwise
        float Areg = 0.0f;
        if (lane < kBatch) {
            const float4* rr = (const float4*)(rb_ + (size_t)lane * kDim);
            float4 ra = rr[0], rb2 = rr[1];
            float a0 = sq_rn(ra.x),  a1 = sq_rn(ra.y),
                  a2 = sq_rn(ra.z),  a3 = sq_rn(ra.w),
                  a4 = sq_rn(rb2.x), a5 = sq_rn(rb2.y),
                  a6 = sq_rn(rb2.z), a7 = sq_rn(rb2.w);
            #pragma unroll
            for (int g = 1; g < 16; ++g) {
                ra = rr[2 * g]; rb2 = rr[2 * g + 1];
                a0 = a0 + sq_rn(ra.x);  a1 = a1 + sq_rn(ra.y);
                a2 = a2 + sq_rn(ra.z);  a3 = a3 + sq_rn(ra.w);
                a4 = a4 + sq_rn(rb2.x); a5 = a5 + sq_rn(rb2.y);
                a6 = a6 + sq_rn(rb2.z); a7 = a7 + sq_rn(rb2.w);
            }
            Areg = ((a0 + a1) + (a2 + a3)) + ((a4 + a5) + (a6 + a7));
        }

        // ---- M: 64 accs (16 items x 4 entry-groups), codebook in VGPRs
        X16(MDECL)
        #pragma unroll 1
        for (int p = 0; p < NPH; ++p) {
            const float* cbp = cbTc + (size_t)(4 * p) * kK + lane;
            const float cb0_0 = cbp[0],   cb0_1 = cbp[64],
                        cb0_2 = cbp[128], cb0_3 = cbp[192];
            const float cb1_0 = cbp[256], cb1_1 = cbp[320],
                        cb1_2 = cbp[384], cb1_3 = cbp[448];
            const float cb2_0 = cbp[512], cb2_1 = cbp[576],
                        cb2_2 = cbp[640], cb2_3 = cbp[704];
            const float cb3_0 = cbp[768], cb3_1 = cbp[832],
                        cb3_2 = cbp[896], cb3_3 = cbp[960];
            X16(MITEM)
        }

        // ---- argmin (B per-lane, coalesced)
        const float* Btc = Bt + c * kK;
        const float B0 = Btc[lane],       B1 = Btc[64 + lane];
        const float B2 = Btc[128 + lane], B3 = Btc[192 + lane];
        X16(ARGMIN)

        // ---- residual update into wave-private scratch rows
        if (c < 2) {
            #pragma unroll 1
            for (int i = 0; i < kBatch; ++i) {
                const int s = __shfl((c == 0) ? sel0 : sel1, i);
                const float* cwrow = cb + ((size_t)c * kK + s) * kDim;
                const float2 w = *(const float2*)(cwrow + 2 * lane);
                float* dr = qb + (size_t)i * kDim;
                const float* sr = (c == 0) ? (xb + (size_t)i * kDim)
                                           : (const float*)dr;
                float2 rv = *(const float2*)(sr + 2 * lane);
                rv.x = rv.x - w.x;             // one rounding each, ref order
                rv.y = rv.y - w.y;
                *(float2*)(dr + 2 * lane) = rv;
            }
            // scratch writes must be visible to this wave's next-cb loads
            asm volatile("s_waitcnt vmcnt(0)" ::: "memory");
        }
    }

    // ---- outputs: quantized (overwrites scratch; all r2 reads done) + idx
    #pragma unroll 1
    for (int i = 0; i < kBatch; ++i) {
        const int s0 = __shfl(sel0, i);
        const int s1 = __shfl(sel1, i);
        const int s2 = __shfl(sel2, i);
        const float2 u = *(const float2*)(cb + ((size_t)0 * kK + s0) * kDim + 2 * lane);
        const float2 v = *(const float2*)(cb + ((size_t)1 * kK + s1) * kDim + 2 * lane);
        const float2 w = *(const float2*)(cb + ((size_t)2 * kK + s2) * kDim + 2 * lane);
        float2 o;
        o.x = (u.x + v.x) + w.x;               // ((0+q0)+q1)+q2, ref order
        o.y = (u.y + v.y) + w.y;
        *(float2*)(qb + (size_t)i * kDim + 2 * lane) = o;
        if (lane == 0) {
            out_idx[(ibase + i) * kNcb + 0] = (float)s0;
            out_idx[(ibase + i) * kNcb + 1] = (float)s1;
            out_idx[(ibase + i) * kNcb + 2] = (float)s2;
        }
    }
}

extern "C" void kernel_launch(void* const* d_in, const int* in_sizes, int n_in,
                              void* d_out, int out_size, void* d_ws, size_t ws_size,
                              hipStream_t stream) {
    const float* x  = (const float*)d_in[0];
    const float* cb = (const float*)d_in[1];
    float* out = (float*)d_out;
    float* Bt  = (float*)d_ws;                 // 768 floats
    float* cbT = (float*)d_ws + 1024;          // 98304 floats (384 KB)
    rvq_prep<<<384, 256, 0, stream>>>(cb, Bt, cbT);
    // 16384 waves (one 16-item batch each) = 4096 blocks x 4 waves
    rvq_kernel<<<kItems / (kBatch * 4), kBlock, 0, stream>>>(x, cb, Bt, cbT, out);
}